// Round 10
// baseline (114.339 us; speedup 1.0000x reference)
//
#include <hip/hip_runtime.h>
#include <hip/hip_fp16.h>
#include <math.h>

#define B_  8
#define H_  64
#define W_  64
#define C_  128
#define F_  256
#define NOC 27

typedef float    f32x4 __attribute__((ext_vector_type(4)));
typedef _Float16 f16x8 __attribute__((ext_vector_type(8)));

// ws layout (float units):
//   woffT  : f16[9][32][128]     @ 0        (73728 B)
//   filtT2 : f16[256][1152]      @ 32768    (589824 B)   [f][k], k=tap*128+c
//   wi32   : float[32768][32]    @ 180224   (4 MB)
//   inh    : f16[8][64][64][128] @ 1228800  (8.4 MB)
#define FILTT_OFF_F 32768
#define WI32_OFF_F  180224
#define INH_OFF_F   1228800

static __device__ __forceinline__ unsigned pkh2(float a, float b) {
    __half2 h = __floats2half2_rn(a, b);
    union { __half2 h2; unsigned u; } cv; cv.h2 = h;
    return cv.u;
}

static __device__ __forceinline__ void async16(void* lds, const void* g) {
    __builtin_amdgcn_global_load_lds(
        (const __attribute__((address_space(1))) unsigned int*)g,
        (__attribute__((address_space(3))) unsigned int*)lds, 16, 0, 0);
}

// ---------------------------------------------------------------- prep
__global__ __launch_bounds__(256) void prep(const float* __restrict__ kofs,
                                            const float* __restrict__ filt,
                                            const float* __restrict__ in,
                                            unsigned short* __restrict__ woffT,
                                            unsigned short* __restrict__ filtT2,
                                            unsigned short* __restrict__ inh) {
    int bidx = blockIdx.x;
    if (bidx >= 1296) {
        int gid = (bidx - 1296) * 256 + threadIdx.x;
        const float4* ip = reinterpret_cast<const float4*>(in) + (size_t)gid * 4;
        float4 a = ip[0], b = ip[1], c = ip[2], d = ip[3];
        uint4 r0 = make_uint4(pkh2(a.x, a.y), pkh2(a.z, a.w), pkh2(b.x, b.y), pkh2(b.z, b.w));
        uint4 r1 = make_uint4(pkh2(c.x, c.y), pkh2(c.z, c.w), pkh2(d.x, d.y), pkh2(d.z, d.w));
        uint4* op = reinterpret_cast<uint4*>(inh) + (size_t)gid * 2;
        op[0] = r0; op[1] = r1;
        return;
    }
    int idx = bidx * 256 + threadIdx.x;
    if (idx < 9 * 32 * 128) {
        int tap = idx >> 12;
        int r   = idx & 4095;
        int oc  = r >> 7;
        int c   = r & 127;
        float v = (oc < NOC) ? kofs[(tap * C_ + c) * NOC + oc] : 0.f;
        union { __half h; unsigned short u; } cv; cv.h = __float2half(v);
        woffT[idx] = cv.u;
        return;
    }
    int idx2 = idx - 9 * 32 * 128;
    if (idx2 < 9 * 256 * 128) {
        int tap = idx2 / 32768;
        int r   = idx2 & 32767;
        int f   = r >> 7;
        int c   = r & 127;
        float v = filt[(tap * C_ + c) * F_ + f];
        union { __half h; unsigned short u; } cv; cv.h = __float2half(v);
        filtT2[(size_t)f * 1152 + tap * 128 + c] = cv.u;
    }
}

// ---------------------------------------------------------------- offset conv (f16 MFMA)
__global__ __launch_bounds__(256) void offset_conv_mfma(const unsigned short* __restrict__ inh,
                                                        const unsigned short* __restrict__ woffT,
                                                        const float* __restrict__ bias,
                                                        float* __restrict__ wi32) {
    __shared__ __align__(16) unsigned char win[3 * 66 * 256];   // 50688 B

    int t    = threadIdx.x;
    int bid  = blockIdx.x;
    int lg   = ((bid & 7) << 6) | (bid >> 3);       // 512 = 8*64
    int bb   = lg >> 6;
    int hh   = lg & 63;
    int pix0 = lg << 6;

    for (int idx = t; idx < 3 * 66 * 16; idx += 256) {
        int ky = idx / (66 * 16);
        int r  = idx % (66 * 16);
        int xi = r >> 4;
        int c8 = r & 15;
        int y  = hh + ky - 1;
        int x  = xi - 1;
        uint4 v = make_uint4(0u, 0u, 0u, 0u);
        if ((unsigned)y < 64u && (unsigned)x < 64u)
            v = *(const uint4*)((const char*)inh +
                    ((size_t)(((bb << 6) + y) * 64 + x) << 8) + (c8 << 4));
        *(uint4*)(win + ky * 16896 + xi * 256 + ((c8 << 4) ^ ((xi & 7) << 4))) = v;
    }
    __syncthreads();

    int lane = t & 63, wv = t >> 6;
    int row  = lane & 15, kg = lane >> 4;
    int px0  = wv << 4;

    f32x4 z = {0.f, 0.f, 0.f, 0.f};
    f32x4 acc[2] = {z, z};

    for (int tap = 0; tap < 9; ++tap) {
        int ky = tap / 3, kx = tap - ky * 3;
        int xi = px0 + row + kx;
        const unsigned char* arow = win + ky * 16896 + xi * 256;
        int sw = (xi & 7) << 4;
        const unsigned short* bp = woffT + (size_t)tap * 4096 + (size_t)row * 128 + kg * 8;
        #pragma unroll
        for (int ks = 0; ks < 4; ++ks) {
            f16x8 a  = *(const f16x8*)(arow + ((ks * 64 + kg * 16) ^ sw));
            f16x8 b0 = *(const f16x8*)(bp + ks * 32);
            f16x8 b1 = *(const f16x8*)(bp + 2048 + ks * 32);
            acc[0] = __builtin_amdgcn_mfma_f32_16x16x32_f16(a, b0, acc[0], 0, 0, 0);
            acc[1] = __builtin_amdgcn_mfma_f32_16x16x32_f16(a, b1, acc[1], 0, 0, 0);
        }
    }

    #pragma unroll
    for (int n = 0; n < 2; ++n) {
        int oc = n * 16 + row;
        float bv = (oc < NOC) ? bias[oc] : 0.f;
        #pragma unroll
        for (int r = 0; r < 4; ++r) {
            int px = px0 + kg * 4 + r;
            wi32[(size_t)(pix0 + px) * 32 + oc] = acc[n][r] + bv;
        }
    }
}

// ---------------------------------------------------------------- fused sampler + GEMM
struct Par { unsigned o00, o01, o10, o11, wa, wb; };

static __device__ __forceinline__ Par mkpar(float o1, float o2, float mm,
                                            int hh, int col, int bb, int tap) {
    float mask = 1.f / (1.f + __expf(-mm));
    int ky = tap / 3, kx = tap - ky * 3;
    float py  = (float)(hh - 1 + ky) + o1;
    float pxx = (float)(col - 1 + kx) + o2;
    float y0f = floorf(py), x0f = floorf(pxx);
    float wy1 = py - y0f,  wy0 = 1.f - wy1;
    float wx1 = pxx - x0f, wx0 = 1.f - wx1;
    float vy0 = (y0f >=  0.f && y0f <= 63.f) ? 1.f : 0.f;
    float vy1 = (y0f >= -1.f && y0f <= 62.f) ? 1.f : 0.f;
    float vx0 = (x0f >=  0.f && x0f <= 63.f) ? 1.f : 0.f;
    float vx1 = (x0f >= -1.f && x0f <= 62.f) ? 1.f : 0.f;
    int y0 = (int)fminf(fmaxf(y0f,       0.f), 63.f);
    int y1 = (int)fminf(fmaxf(y0f + 1.f, 0.f), 63.f);
    int x0 = (int)fminf(fmaxf(x0f,       0.f), 63.f);
    int x1 = (int)fminf(fmaxf(x0f + 1.f, 0.f), 63.f);
    int base = bb << 12;
    Par p;
    p.o00 = (unsigned)((base + (y0 << 6) + x0) << 8);
    p.o01 = (unsigned)((base + (y0 << 6) + x1) << 8);
    p.o10 = (unsigned)((base + (y1 << 6) + x0) << 8);
    p.o11 = (unsigned)((base + (y1 << 6) + x1) << 8);
    p.wa  = pkh2(wy0 * wx0 * mask * vy0 * vx0, wy0 * wx1 * mask * vy0 * vx1);
    p.wb  = pkh2(wy1 * wx0 * mask * vy1 * vx0, wy1 * wx1 * mask * vy1 * vx1);
    return p;
}

static __device__ __forceinline__ void issue_corners(uint4 cc[4][4], const char* ih,
                                                     const Par& p, int chb) {
    #pragma unroll
    for (int j = 0; j < 4; ++j) cc[0][j] = *(const uint4*)(ih + p.o00 + chb + j * 16);
    #pragma unroll
    for (int j = 0; j < 4; ++j) cc[1][j] = *(const uint4*)(ih + p.o01 + chb + j * 16);
    #pragma unroll
    for (int j = 0; j < 4; ++j) cc[2][j] = *(const uint4*)(ih + p.o10 + chb + j * 16);
    #pragma unroll
    for (int j = 0; j < 4; ++j) cc[3][j] = *(const uint4*)(ih + p.o11 + chb + j * 16);
}

static __device__ __forceinline__ void blend_write(unsigned char* dst, int spx, int cp,
                                                   const uint4 cc[4][4],
                                                   unsigned wa, unsigned wb) {
    union H2 { unsigned u; __half2 h; };
    H2 w00, w01, w10, w11;
    w00.u = (wa & 0xFFFFu) * 0x10001u;
    w01.u = (wa >> 16)     * 0x10001u;
    w10.u = (wb & 0xFFFFu) * 0x10001u;
    w11.u = (wb >> 16)     * 0x10001u;
    #pragma unroll
    for (int j = 0; j < 4; ++j) {
        union { uint4 u; __half2 h[4]; } a0, a1, a2, a3, s;
        a0.u = cc[0][j]; a1.u = cc[1][j]; a2.u = cc[2][j]; a3.u = cc[3][j];
        #pragma unroll
        for (int q = 0; q < 4; ++q) {
            __half2 v = __hmul2(a0.h[q], w00.h);
            v = __hfma2(a1.h[q], w01.h, v);
            v = __hfma2(a2.h[q], w10.h, v);
            s.h[q] = __hfma2(a3.h[q], w11.h, v);
        }
        int c8 = cp * 4 + j;
        *(uint4*)(dst + spx * 128 + ((c8 * 16) ^ ((spx & 7) << 4))) = s.u;
    }
}

static __device__ __forceinline__ void do_mfma(const unsigned char* As, const unsigned char* Bs,
                                               int wm, int wn, int row16, int kg,
                                               f32x4 acc[4][4]) {
    int sw = (row16 & 7) << 4;
    #pragma unroll
    for (int ks = 0; ks < 2; ++ks) {
        int kcol = ((ks << 6) + (kg << 4)) ^ sw;
        f16x8 a[4], b[4];
        #pragma unroll
        for (int m = 0; m < 4; ++m)
            a[m] = *(const f16x8*)(As + ((wm << 6) + (m << 4) + row16) * 128 + kcol);
        #pragma unroll
        for (int n = 0; n < 4; ++n)
            b[n] = *(const f16x8*)(Bs + ((wn << 6) + (n << 4) + row16) * 128 + kcol);
        #pragma unroll
        for (int m = 0; m < 4; ++m)
            #pragma unroll
            for (int n = 0; n < 4; ++n)
                acc[m][n] = __builtin_amdgcn_mfma_f32_16x16x32_f16(a[m], b[n], acc[m][n], 0, 0, 0);
    }
}

// block = 128 px x 256 F, 256 thr / 4 waves, grid 512 (2 blocks/CU).
// m97 structure, BK=64, dbuf LDS, 1 barrier/step; A staged by in-kernel
// bilinear gather (issue loads for step s+1 before step s's MFMAs).
__global__ __launch_bounds__(256, 2) void gemm_fused(const unsigned short* __restrict__ inh,
                                                     const unsigned short* __restrict__ filtT2,
                                                     const float* __restrict__ wi32,
                                                     float* __restrict__ out) {
    __shared__ __align__(16) unsigned char As0[16384], As1[16384];
    __shared__ __align__(16) unsigned char Bs0[16384], Bs1[16384];

    int t   = threadIdx.x;
    int bid = blockIdx.x;
    int lg  = ((bid & 7) << 6) | (bid >> 3);      // 512 = 8*64, XCD-bijective
    int mt  = lg >> 1, nt = lg & 1;
    int apix = mt << 7;
    int f0   = nt << 7;

    // A-stager identity: row spx, chunk-half cp
    int spx = t & 127;
    int cp  = t >> 7;
    int pix = apix + spx;
    int bb  = pix >> 12, hh = (pix >> 6) & 63, col = pix & 63;
    const float* wrow = wi32 + (size_t)pix * 32;
    const char*  ih   = (const char*)inh;

    // B-stager identity
    int lane = t & 63, wv = t >> 6;
    int lin0 = wv * 1024 + lane * 16;
    const char* Bb = (const char*)filtT2;

    // MFMA identity
    int wm = wv & 1, wn = wv >> 1;
    int row16 = lane & 15, kg = lane >> 4;

    f32x4 z = {0.f, 0.f, 0.f, 0.f};
    f32x4 acc[4][4];
    #pragma unroll
    for (int m = 0; m < 4; ++m)
        #pragma unroll
        for (int n = 0; n < 4; ++n) acc[m][n] = z;

    uint4 cc[4][4];
    Par par;
    float no1, no2, nmm;

    // B staging helper (4 async16 per thread = 16 KB tile)
    auto asyncB = [&](unsigned char* buf, int s) {
        #pragma unroll
        for (int it = 0; it < 4; ++it) {
            int lin  = lin0 + it * 4096;
            int brow = lin >> 7;
            int bcol = (lin & 127) ^ ((brow & 7) << 4);
            async16(buf + wv * 1024 + it * 4096,
                    Bb + (size_t)(f0 + brow) * 2304 + s * 128 + bcol);
        }
    };

    // ---- prologue: stage s=0 (tap0, half0)
    {
        float o1 = wrow[0], o2 = wrow[9], mm = wrow[18];
        par = mkpar(o1, o2, mm, hh, col, bb, 0);
        issue_corners(cc, ih, par, cp * 64);
        asyncB(Bs0, 0);
        no1 = wrow[1]; no2 = wrow[10]; nmm = wrow[19];
        blend_write(As0, spx, cp, cc, par.wa, par.wb);
        __syncthreads();
    }

    for (int tap = 0; tap < 9; ++tap) {
        // ===== step h0: consume As0/Bs0; prefetch h1 (same tap, chan-half 1)
        issue_corners(cc, ih, par, 128 + cp * 64);
        asyncB(Bs1, 2 * tap + 1);
        __builtin_amdgcn_sched_barrier(0);
        do_mfma(As0, Bs0, wm, wn, row16, kg, acc);
        blend_write(As1, spx, cp, cc, par.wa, par.wb);
        __syncthreads();

        // ===== step h1: consume As1/Bs1; prefetch next tap half0
        if (tap < 8) {
            par = mkpar(no1, no2, nmm, hh, col, bb, tap + 1);
            if (tap < 7) {
                no1 = wrow[tap + 2]; no2 = wrow[11 + tap]; nmm = wrow[20 + tap];
            }
            issue_corners(cc, ih, par, cp * 64);
            asyncB(Bs0, 2 * tap + 2);
            __builtin_amdgcn_sched_barrier(0);
        }
        do_mfma(As1, Bs1, wm, wn, row16, kg, acc);
        if (tap < 8) blend_write(As0, spx, cp, cc, par.wa, par.wb);
        __syncthreads();
    }

    // ---- epilogue: px = wm*64 + m*16 + 4*kg + r, f = f0 + wn*64 + n*16 + row16
    int pxb = apix + (wm << 6);
    int fcb = f0 + (wn << 6) + row16;
    #pragma unroll
    for (int m = 0; m < 4; ++m)
        #pragma unroll
        for (int r = 0; r < 4; ++r) {
            int px = pxb + (m << 4) + (kg << 2) + r;
            float* op = out + (size_t)px * 256 + fcb;
            op[0]  = acc[m][0][r];
            op[16] = acc[m][1][r];
            op[32] = acc[m][2][r];
            op[48] = acc[m][3][r];
        }
}

// ---------------------------------------------------------------- launch
extern "C" void kernel_launch(void* const* d_in, const int* in_sizes, int n_in,
                              void* d_out, int out_size, void* d_ws, size_t ws_size,
                              hipStream_t stream) {
    const float* in   = (const float*)d_in[0];
    const float* kofs = (const float*)d_in[1];
    const float* bias = (const float*)d_in[2];
    const float* filt = (const float*)d_in[3];
    float* out = (float*)d_out;
    float* ws  = (float*)d_ws;

    unsigned short* woffT  = (unsigned short*)ws;
    unsigned short* filtT2 = (unsigned short*)(ws + FILTT_OFF_F);
    float*          wi32   = ws + WI32_OFF_F;
    unsigned short* inh    = (unsigned short*)(ws + INH_OFF_F);

    hipLaunchKernelGGL(prep, dim3(2320), dim3(256), 0, stream, kofs, filt, in, woffT, filtT2, inh);
    hipLaunchKernelGGL(offset_conv_mfma, dim3(512), dim3(256), 0, stream, inh, woffT, bias, wi32);
    hipLaunchKernelGGL(gemm_fused, dim3(512), dim3(256), 0, stream, inh, filtT2, wi32, out);
}

// Round 11
// 73.351 us; speedup vs baseline: 1.5588x; 1.5588x over previous
//
#include <hip/hip_runtime.h>
#include <hip/hip_fp16.h>
#include <math.h>

#define B_  8
#define H_  64
#define W_  64
#define C_  128
#define F_  256
#define NOC 27

typedef float    f32x4 __attribute__((ext_vector_type(4)));
typedef _Float16 f16x8 __attribute__((ext_vector_type(8)));

// ws layout (float units):
//   woffT  : f16[9][32][128]     @ 0        (73728 B)
//   filtT2 : f16[256][1152]      @ 32768    (589824 B)   [f][k], k=tap*128+c
//   inh    : f16[8][64][64][128] @ 1228800  (8.4 MB)
//   Aim    : f16[32768][1152]    @ 3325952  (75.5 MB)
#define FILTT_OFF_F 32768
#define INH_OFF_F   1228800
#define AIM_OFF_F   3325952

static __device__ __forceinline__ unsigned pkh2(float a, float b) {
    __half2 h = __floats2half2_rn(a, b);
    union { __half2 h2; unsigned u; } cv; cv.h2 = h;
    return cv.u;
}

static __device__ __forceinline__ void async16(void* lds, const void* g) {
    __builtin_amdgcn_global_load_lds(
        (const __attribute__((address_space(1))) unsigned int*)g,
        (__attribute__((address_space(3))) unsigned int*)lds, 16, 0, 0);
}

// ---------------------------------------------------------------- prep
// blocks [0,1296): weight repack; [1296,2320): input f32->f16
__global__ __launch_bounds__(256) void prep(const float* __restrict__ kofs,
                                            const float* __restrict__ filt,
                                            const float* __restrict__ in,
                                            unsigned short* __restrict__ woffT,
                                            unsigned short* __restrict__ filtT2,
                                            unsigned short* __restrict__ inh) {
    int bidx = blockIdx.x;
    if (bidx >= 1296) {
        int gid = (bidx - 1296) * 256 + threadIdx.x;
        const float4* ip = reinterpret_cast<const float4*>(in) + (size_t)gid * 4;
        float4 a = ip[0], b = ip[1], c = ip[2], d = ip[3];
        uint4 r0 = make_uint4(pkh2(a.x, a.y), pkh2(a.z, a.w), pkh2(b.x, b.y), pkh2(b.z, b.w));
        uint4 r1 = make_uint4(pkh2(c.x, c.y), pkh2(c.z, c.w), pkh2(d.x, d.y), pkh2(d.z, d.w));
        uint4* op = reinterpret_cast<uint4*>(inh) + (size_t)gid * 2;
        op[0] = r0; op[1] = r1;
        return;
    }
    int idx = bidx * 256 + threadIdx.x;
    if (idx < 9 * 32 * 128) {
        int tap = idx >> 12;
        int r   = idx & 4095;
        int oc  = r >> 7;
        int c   = r & 127;
        float v = (oc < NOC) ? kofs[(tap * C_ + c) * NOC + oc] : 0.f;
        union { __half h; unsigned short u; } cv; cv.h = __float2half(v);
        woffT[idx] = cv.u;
        return;
    }
    int idx2 = idx - 9 * 32 * 128;
    if (idx2 < 9 * 256 * 128) {
        int tap = idx2 / 32768;
        int r   = idx2 & 32767;
        int f   = r >> 7;
        int c   = r & 127;
        float v = filt[(tap * C_ + c) * F_ + f];
        union { __half h; unsigned short u; } cv; cv.h = __float2half(v);
        filtT2[(size_t)f * 1152 + tap * 128 + c] = cv.u;
    }
}

// ---------------------------------------------------------------- fused offset-conv + sampler
// block = one image row (64 px), 256 thr / 4 waves.
// Phase A: stage 3x66 window, MFMA offset conv -> wi (LDS).
// Phase B: per-(px,tap) sampling params -> LDS.
// Phase C: modulated bilinear gather (global, L2-hot) -> Aim f16.
__global__ __launch_bounds__(256) void sample_row(const unsigned short* __restrict__ inh,
                                                  const unsigned short* __restrict__ woffT,
                                                  const float* __restrict__ bias,
                                                  unsigned short* __restrict__ Aim) {
    __shared__ __align__(16) unsigned char win[3 * 66 * 256];   // 50688 B
    __shared__ float wi[64][33];                                // 8448 B (+1 pad: bank spread)
    __shared__ __align__(16) uint4 prmo[64][9];                 // 9216 B
    __shared__ __align__(16) uint2 prmw[64][9];                 // 4608 B

    int t    = threadIdx.x;
    int bid  = blockIdx.x;
    int lg   = ((bid & 7) << 6) | (bid >> 3);       // 512 = 8*64, XCD-bijective
    int bb   = lg >> 6;
    int hh   = lg & 63;
    int pix0 = lg << 6;

    // ---- Phase A1: stage window rows hh-1..hh+1, x=-1..64
    for (int idx = t; idx < 3 * 66 * 16; idx += 256) {
        int ky = idx / (66 * 16);
        int r  = idx % (66 * 16);
        int xi = r >> 4;
        int c8 = r & 15;
        int y  = hh + ky - 1;
        int x  = xi - 1;
        uint4 v = make_uint4(0u, 0u, 0u, 0u);
        if ((unsigned)y < 64u && (unsigned)x < 64u)
            v = *(const uint4*)((const char*)inh +
                    ((size_t)(((bb << 6) + y) * 64 + x) << 8) + (c8 << 4));
        *(uint4*)(win + ky * 16896 + xi * 256 + ((c8 << 4) ^ ((xi & 7) << 4))) = v;
    }
    __syncthreads();

    // ---- Phase A2: offset conv MFMA -> wi LDS
    {
        int lane = t & 63, wv = t >> 6;
        int row  = lane & 15, kg = lane >> 4;
        int px0  = wv << 4;

        f32x4 z = {0.f, 0.f, 0.f, 0.f};
        f32x4 acc[2] = {z, z};

        for (int tap = 0; tap < 9; ++tap) {
            int ky = tap / 3, kx = tap - ky * 3;
            int xi = px0 + row + kx;
            const unsigned char* arow = win + ky * 16896 + xi * 256;
            int sw = (xi & 7) << 4;
            const unsigned short* bp = woffT + (size_t)tap * 4096 + (size_t)row * 128 + kg * 8;
            #pragma unroll
            for (int ks = 0; ks < 4; ++ks) {
                f16x8 a  = *(const f16x8*)(arow + ((ks * 64 + kg * 16) ^ sw));
                f16x8 b0 = *(const f16x8*)(bp + ks * 32);
                f16x8 b1 = *(const f16x8*)(bp + 2048 + ks * 32);
                acc[0] = __builtin_amdgcn_mfma_f32_16x16x32_f16(a, b0, acc[0], 0, 0, 0);
                acc[1] = __builtin_amdgcn_mfma_f32_16x16x32_f16(a, b1, acc[1], 0, 0, 0);
            }
        }
        #pragma unroll
        for (int n = 0; n < 2; ++n) {
            int oc = n * 16 + row;
            float bv = (oc < NOC) ? bias[oc] : 0.f;
            #pragma unroll
            for (int r = 0; r < 4; ++r)
                wi[px0 + kg * 4 + r][oc] = acc[n][r] + bv;
        }
    }
    __syncthreads();

    // ---- Phase B: sampling params (576 items)
    for (int it = t; it < 576; it += 256) {
        int px  = it & 63;
        int tap = it >> 6;
        float o1 = wi[px][tap], o2 = wi[px][9 + tap], mm = wi[px][18 + tap];
        float mask = 1.f / (1.f + __expf(-mm));
        int ky = tap / 3, kx = tap - ky * 3;
        float py  = (float)(hh - 1 + ky) + o1;
        float pxx = (float)(px - 1 + kx) + o2;
        float y0f = floorf(py), x0f = floorf(pxx);
        float wy1 = py - y0f,  wy0 = 1.f - wy1;
        float wx1 = pxx - x0f, wx0 = 1.f - wx1;
        float vy0 = (y0f >=  0.f && y0f <= 63.f) ? 1.f : 0.f;
        float vy1 = (y0f >= -1.f && y0f <= 62.f) ? 1.f : 0.f;
        float vx0 = (x0f >=  0.f && x0f <= 63.f) ? 1.f : 0.f;
        float vx1 = (x0f >= -1.f && x0f <= 62.f) ? 1.f : 0.f;
        int y0 = (int)fminf(fmaxf(y0f,       0.f), 63.f);
        int y1 = (int)fminf(fmaxf(y0f + 1.f, 0.f), 63.f);
        int x0 = (int)fminf(fmaxf(x0f,       0.f), 63.f);
        int x1 = (int)fminf(fmaxf(x0f + 1.f, 0.f), 63.f);
        int base = bb << 12;
        prmo[px][tap] = make_uint4((unsigned)((base + (y0 << 6) + x0) << 8),
                                   (unsigned)((base + (y0 << 6) + x1) << 8),
                                   (unsigned)((base + (y1 << 6) + x0) << 8),
                                   (unsigned)((base + (y1 << 6) + x1) << 8));
        prmw[px][tap] = make_uint2(pkh2(wy0 * wx0 * mask * vy0 * vx0,
                                        wy0 * wx1 * mask * vy0 * vx1),
                                   pkh2(wy1 * wx0 * mask * vy1 * vx0,
                                        wy1 * wx1 * mask * vy1 * vx1));
    }
    __syncthreads();

    // ---- Phase C: gather + blend + write Aim
    int c8  = t & 15;
    int pxg = (t >> 4) & 7;
    int th  = t >> 7;                 // 0: taps 0..4, 1: taps 5..8
    int cb  = c8 << 4;

    const char* ih = (const char*)inh;
    int tbeg = th ? 5 : 0, tend = th ? 9 : 5;
    union AU { uint4 u; __half2 h[4]; };

    #pragma unroll 2
    for (int pp = 0; pp < 8; ++pp) {
        int px = pxg + (pp << 3);
        char* Ao = (char*)Aim + (size_t)(pix0 + px) * 2304;
        #pragma unroll 5
        for (int tap = tbeg; tap < tend; ++tap) {
            uint4 O  = prmo[px][tap];
            uint2 Wp = prmw[px][tap];
            union { unsigned u; __half2 h; } w00, w01, w10, w11;
            w00.u = (Wp.x & 0xFFFFu) * 0x10001u;
            w01.u = (Wp.x >> 16)     * 0x10001u;
            w10.u = (Wp.y & 0xFFFFu) * 0x10001u;
            w11.u = (Wp.y >> 16)     * 0x10001u;
            AU c00, c01, c10, c11, s;
            c00.u = *(const uint4*)(ih + O.x + cb);
            c01.u = *(const uint4*)(ih + O.y + cb);
            c10.u = *(const uint4*)(ih + O.z + cb);
            c11.u = *(const uint4*)(ih + O.w + cb);
            #pragma unroll
            for (int j = 0; j < 4; ++j) {
                __half2 sj = __hmul2(c00.h[j], w00.h);
                sj = __hfma2(c01.h[j], w01.h, sj);
                sj = __hfma2(c10.h[j], w10.h, sj);
                s.h[j] = __hfma2(c11.h[j], w11.h, sj);
            }
            *(uint4*)(Ao + tap * 256 + cb) = s.u;
        }
    }
}

// ---------------------------------------------------------------- im2col GEMM, double-buffered
// C[32768 x 256] = Aim * filtT2^T. 128x128 tile, BK=64, global_load_lds w16,
// T2 source-pre-swizzle, dbuf + issue-early STAGE, ONE barrier per K-step.
__global__ __launch_bounds__(256) void gemm_im2col(const unsigned short* __restrict__ Aim,
                                                   const unsigned short* __restrict__ filtT2,
                                                   float* __restrict__ out) {
    __shared__ __align__(16) unsigned char As[2][16384];
    __shared__ __align__(16) unsigned char Bs[2][16384];

    int t   = threadIdx.x;
    int bid = blockIdx.x;
    int lg  = ((bid & 7) << 6) | (bid >> 3);      // 512 = 8*64, XCD-bijective
    int mt  = lg >> 1, nt = lg & 1;
    int apix = mt << 7;
    int f0   = nt << 7;

    int lane = t & 63, wv = t >> 6;
    int wm = wv & 1, wn = wv >> 1;
    int row16 = lane & 15, kg = lane >> 4;

    const char* Ab = (const char*)Aim;
    const char* Bb = (const char*)filtT2;

    f32x4 z = {0.f, 0.f, 0.f, 0.f};
    f32x4 acc[4][4];
    #pragma unroll
    for (int m = 0; m < 4; ++m)
        #pragma unroll
        for (int n = 0; n < 4; ++n) acc[m][n] = z;

    int lin0 = wv * 1024 + lane * 16;

    auto stageTo = [&](unsigned char* A, unsigned char* B, int s) {
        int k2 = s << 7;
        #pragma unroll
        for (int it = 0; it < 4; ++it) {
            int lin = lin0 + it * 4096;
            int r_  = lin >> 7;
            int c_  = (lin & 127) ^ ((r_ & 7) << 4);
            async16(A + wv * 1024 + it * 4096,
                    Ab + (size_t)(apix + r_) * 2304 + k2 + c_);
            async16(B + wv * 1024 + it * 4096,
                    Bb + (size_t)(f0 + r_) * 2304 + k2 + c_);
        }
    };

    auto mfmaOn = [&](const unsigned char* A, const unsigned char* B) {
        int sw = (row16 & 7) << 4;
        #pragma unroll
        for (int ks = 0; ks < 2; ++ks) {
            int kcol = ((ks << 6) + (kg << 4)) ^ sw;
            f16x8 a[4], b[4];
            #pragma unroll
            for (int m = 0; m < 4; ++m)
                a[m] = *(const f16x8*)(A + ((wm << 6) + (m << 4) + row16) * 128 + kcol);
            #pragma unroll
            for (int n = 0; n < 4; ++n)
                b[n] = *(const f16x8*)(B + ((wn << 6) + (n << 4) + row16) * 128 + kcol);
            #pragma unroll
            for (int m = 0; m < 4; ++m)
                #pragma unroll
                for (int n = 0; n < 4; ++n)
                    acc[m][n] = __builtin_amdgcn_mfma_f32_16x16x32_f16(a[m], b[n], acc[m][n], 0, 0, 0);
        }
    };

    stageTo(As[0], Bs[0], 0);
    __syncthreads();

    #pragma unroll 1
    for (int kb = 0; kb < 18; kb += 2) {
        stageTo(As[1], Bs[1], kb + 1);         // issue next BEFORE compute
        mfmaOn(As[0], Bs[0]);
        __syncthreads();                        // vmcnt(0)+lgkm drain, buf1 ready
        if (kb < 16) stageTo(As[0], Bs[0], kb + 2);
        mfmaOn(As[1], Bs[1]);
        __syncthreads();
    }

    int pxb = apix + (wm << 6);
    int fcb = f0 + (wn << 6) + row16;
    #pragma unroll
    for (int m = 0; m < 4; ++m)
        #pragma unroll
        for (int r = 0; r < 4; ++r) {
            int px = pxb + (m << 4) + (kg << 2) + r;
            float* op = out + (size_t)px * 256 + fcb;
            op[0]  = acc[m][0][r];
            op[16] = acc[m][1][r];
            op[32] = acc[m][2][r];
            op[48] = acc[m][3][r];
        }
}

// ---------------------------------------------------------------- launch
extern "C" void kernel_launch(void* const* d_in, const int* in_sizes, int n_in,
                              void* d_out, int out_size, void* d_ws, size_t ws_size,
                              hipStream_t stream) {
    const float* in   = (const float*)d_in[0];
    const float* kofs = (const float*)d_in[1];
    const float* bias = (const float*)d_in[2];
    const float* filt = (const float*)d_in[3];
    float* out = (float*)d_out;
    float* ws  = (float*)d_ws;

    unsigned short* woffT  = (unsigned short*)ws;
    unsigned short* filtT2 = (unsigned short*)(ws + FILTT_OFF_F);
    unsigned short* inh    = (unsigned short*)(ws + INH_OFF_F);
    unsigned short* Aim    = (unsigned short*)(ws + AIM_OFF_F);

    hipLaunchKernelGGL(prep, dim3(2320), dim3(256), 0, stream, kofs, filt, in, woffT, filtT2, inh);
    hipLaunchKernelGGL(sample_row, dim3(512), dim3(256), 0, stream, inh, woffT, bias, Aim);
    hipLaunchKernelGGL(gemm_im2col, dim3(512), dim3(256), 0, stream, Aim, filtT2, out);
}